// Round 8
// baseline (119.294 us; speedup 1.0000x reference)
//
#include <hip/hip_runtime.h>
#include <hip/hip_bf16.h>

#define EPSF 1e-5f

namespace {
constexpr int B = 64, D = 20000, C = 16, H = 64, EH = 128, L = 32;
constexpr int NB = 1280;                        // k_rows blocks (5/CU)
constexpr int MAXU = B * ((D + 63) / 64);       // max 64-pt units (20032)
}

typedef __attribute__((ext_vector_type(8))) short bf16x8;
typedef __attribute__((ext_vector_type(4))) float f32x4;
typedef __attribute__((ext_vector_type(4))) unsigned int u32x4;

static __device__ __forceinline__ unsigned short f2bf(float f) {
    __hip_bfloat16 h = __float2bfloat16(f);
    return __builtin_bit_cast(unsigned short, h);
}
static __device__ __forceinline__ unsigned int packbf(float lo, float hi) {
    return ((unsigned int)f2bf(hi) << 16) | (unsigned int)f2bf(lo);
}
// hot-path pair conversion -> v_cvt_pk_bf16_f32 (component-wise bit_cast;
// __hip_bfloat162 itself is not trivially copyable)
static __device__ __forceinline__ unsigned int cvtpk(float lo, float hi) {
    __hip_bfloat162 h2 = __float22bfloat162_rn(make_float2(lo, hi));
    return ((unsigned int)__builtin_bit_cast(unsigned short, h2.y) << 16)
         | (unsigned int)__builtin_bit_cast(unsigned short, h2.x);
}

// ---------- K1: fused compaction + inline gather/convert + weight prep ----------
// Blocks 0..B-1: batch b — running-prefix compaction; for each observed d,
// gather fe[d] -> bf16 row hfe[b][pos], pack {x,1.0} -> hxp[b][pos];
// zero-pad to 64-unit boundary. Blocks B,B+1: W1T / W2T staging.
__global__ __launch_bounds__(1024) void k_prep(
    const int* __restrict__ mask, const float* __restrict__ x,
    const float* __restrict__ fe,
    const float* __restrict__ W1, const float* __restrict__ b1,
    const float* __restrict__ W2,
    int* __restrict__ cnt,
    unsigned short* __restrict__ hfe, unsigned int* __restrict__ hxp,
    unsigned short* __restrict__ W1T, unsigned short* __restrict__ W2T)
{
    const int t = threadIdx.x;
    if (blockIdx.x < B) {
        const int b = blockIdx.x;
        const int lane = t & 63, wid = t >> 6;
        __shared__ int wc[16];
        const size_t bD = (size_t)b * D;
        constexpr int NIT = (D + 1023) / 1024;   // 20
        int mv = (t < D) ? mask[bD + t] : 0;     // iter-0 prefetch
        int base = 0;
        for (int it = 0; it < NIT; ++it) {
            int mv_next = 0;
            const int dn = (it + 1) * 1024 + t;
            if (it + 1 < NIT && dn < D) mv_next = mask[bD + dn];
            const unsigned long long bal = __ballot(mv != 0);
            if (lane == 0) wc[wid] = __popcll(bal);
            __syncthreads();
            int woff = 0, tot = 0;
            #pragma unroll
            for (int k2 = 0; k2 < 16; ++k2) {
                const int c0 = wc[k2];
                tot += c0;
                if (k2 < wid) woff += c0;
            }
            if (mv) {
                const int d = it * 1024 + t;
                const int pre = __popcll(bal & ((1ull << lane) - 1ull));
                const int pos = base + woff + pre;
                const float4 f0 = *(const float4*)(fe + (size_t)d * C);
                const float4 f1 = *(const float4*)(fe + (size_t)d * C + 4);
                const float4 f2 = *(const float4*)(fe + (size_t)d * C + 8);
                const float4 f3 = *(const float4*)(fe + (size_t)d * C + 12);
                uint4 p0, p1;
                p0.x = packbf(f0.x, f0.y); p0.y = packbf(f0.z, f0.w);
                p0.z = packbf(f1.x, f1.y); p0.w = packbf(f1.z, f1.w);
                p1.x = packbf(f2.x, f2.y); p1.y = packbf(f2.z, f2.w);
                p1.z = packbf(f3.x, f3.y); p1.w = packbf(f3.z, f3.w);
                *(uint4*)(hfe + (bD + pos) * 16)     = p0;
                *(uint4*)(hfe + (bD + pos) * 16 + 8) = p1;
                hxp[bD + pos] = packbf(x[bD + d], 1.0f);
            }
            base += tot;
            __syncthreads();                      // wc reuse guard
            mv = mv_next;
        }
        // zero-pad to unit boundary (keeps tail MFMAs finite, no guards needed)
        const int padend = (base + 63) & ~63;
        for (int i = base + t; i < padend; i += 1024) {
            *(uint4*)(hfe + (bD + i) * 16)     = make_uint4(0, 0, 0, 0);
            *(uint4*)(hfe + (bD + i) * 16 + 8) = make_uint4(0, 0, 0, 0);
            hxp[bD + i] = 0u;
        }
        if (t == 0) cnt[b] = base;
    } else if (blockIdx.x == B) {
        // W1T with permuted row->h mapping so layer1 D-layout == layer2 B-layout:
        // row rIdx = 16m+rho -> h = 32*(m>>1) + 8*(rho>>2) + 4*(m&1) + (rho&3)
        // cols kk: kk<16 -> W1[kk+1][h]; 16 -> W1[0][h] (x); 17 -> b1[h]; else 0
        for (int e = t; e < H * 32; e += 1024) {
            const int rIdx = e >> 5, kk = e & 31;
            const int m = rIdx >> 4, rho = rIdx & 15;
            const int h = 32 * (m >> 1) + 8 * (rho >> 2) + 4 * (m & 1) + (rho & 3);
            float v = 0.f;
            if (kk < 16)       v = W1[(kk + 1) * H + h];
            else if (kk == 16) v = W1[h];
            else if (kk == 17) v = b1[h];
            W1T[e] = f2bf(v);
        }
    } else {
        // W2T[c][h] = W2[h][c]
        for (int e = t; e < C * H; e += 1024) {
            const int c0 = e >> 6, hh = e & 63;
            W2T[e] = f2bf(W2[hh * C + c0]);
        }
    }
}

// ---------- K2: LDS-free MFMA pointnet, streaming pre-gathered inputs ----------
__global__ __launch_bounds__(256, 5) void k_rows(
    const int* __restrict__ cnt,
    const unsigned short* __restrict__ hfe, const unsigned int* __restrict__ hxp,
    const unsigned short* __restrict__ W1T, const unsigned short* __restrict__ W2T,
    const float* __restrict__ g1, const float* __restrict__ be1,
    const float* __restrict__ g2, const float* __restrict__ be2,
    const float* __restrict__ b2,
    float* __restrict__ part)      // [MAXU][C]
{
    const int tid = threadIdx.x;
    const int w = tid >> 6, lane = tid & 63;
    const int g = lane >> 4, q = lane & 15;

    // per-lane schedule state (lane == batch id; B == 64)
    const int cv  = cnt[lane];
    const int nuv = (cv + 63) >> 6;
    int Pi = nuv;
    #pragma unroll
    for (int off = 1; off < 64; off <<= 1) {
        const int pv = __shfl_up(Pi, off);
        if (lane >= off) Pi += pv;
    }
    const int T = __shfl(Pi, 63);

    // weight fragments (A-operands)
    bf16x8 w1f[4];
    #pragma unroll
    for (int m = 0; m < 4; ++m)
        w1f[m] = *(const bf16x8*)(W1T + (16 * m + q) * 32 + 8 * g);
    bf16x8 w2f[2];
    #pragma unroll
    for (int ks = 0; ks < 2; ++ks)
        w2f[ks] = *(const bf16x8*)(W2T + q * 64 + 32 * ks + 8 * g);

    // LN1 affine at permuted rows: reg r of tile m holds h = 32(m>>1)+8g+4(m&1)+r
    float4 g1v[4], be1v[4];
    #pragma unroll
    for (int m = 0; m < 4; ++m) {
        const int h0 = 32 * (m >> 1) + 8 * g + 4 * (m & 1);
        g1v[m]  = *(const float4*)(g1  + h0);
        be1v[m] = *(const float4*)(be1 + h0);
    }
    const float4 g2v  = *(const float4*)(g2  + 4 * g);
    const float4 be2v = *(const float4*)(be2 + 4 * g);
    const float4 b2v  = *(const float4*)(b2  + 4 * g);

    const f32x4 z = {0.f, 0.f, 0.f, 0.f};

    for (int u = blockIdx.x * 4 + w; u < T; u += NB * 4) {
        // unit -> (batch b, base offset)
        const unsigned long long bl = __ballot(Pi <= u);
        const int b   = __popcll(bl);
        const int Pb  = __shfl(Pi, b);
        const int nub = __shfl(nuv, b);
        const int n   = __shfl(cv, b);
        const int base = (u - (Pb - nub)) * 64;
        const size_t rowb = (size_t)b * D + base;
        const int rem = n - base;                // valid points in this unit

        // streaming fetch: 4 groups of 16 points -> registers (coalesced)
        bf16x8 hb[4];
        #pragma unroll
        for (int it = 0; it < 4; ++it) {
            bf16x8 hv = {0, 0, 0, 0, 0, 0, 0, 0};
            const int p = (it << 4) + q;
            if (g < 2) {
                hv = *(const bf16x8*)(hfe + (rowb + p) * 16 + 8 * g);
            } else if (g == 2) {
                const unsigned int xv = hxp[rowb + p];
                const u32x4 tmp = {xv, 0u, 0u, 0u};
                hv = __builtin_bit_cast(bf16x8, tmp);
            }
            hb[it] = hv;
        }

        f32x4 lacc = {0.f, 0.f, 0.f, 0.f};
        #pragma unroll
        for (int it = 0; it < 4; ++it) {
            f32x4 t1a[4];
            #pragma unroll
            for (int m = 0; m < 4; ++m)
                t1a[m] = __builtin_amdgcn_mfma_f32_16x16x32_bf16(w1f[m], hb[it], z, 0, 0, 0);

            // LN over H=64 for point q (disjoint 16-subsets per lane-group)
            float s0 = 0.f, s1 = 0.f, q0 = 0.f, q1 = 0.f;
            #pragma unroll
            for (int m = 0; m < 4; ++m) {
                s0 += t1a[m][0] + t1a[m][1];
                s1 += t1a[m][2] + t1a[m][3];
                q0 = fmaf(t1a[m][0], t1a[m][0], fmaf(t1a[m][1], t1a[m][1], q0));
                q1 = fmaf(t1a[m][2], t1a[m][2], fmaf(t1a[m][3], t1a[m][3], q1));
            }
            float s = s0 + s1, sq = q0 + q1;
            s  += __shfl_xor(s, 16);  sq += __shfl_xor(sq, 16);
            s  += __shfl_xor(s, 32);  sq += __shfl_xor(sq, 32);
            const float mean1 = s * (1.f / H);
            const float var1  = fmaxf(sq * (1.f / H) - mean1 * mean1, 0.f);
            const float rstd1 = rsqrtf(var1 + EPSF);

            // normalize+affine+relu, pack DIRECTLY into layer2 B-fragments
            unsigned int pw[8];
            #pragma unroll
            for (int m = 0; m < 4; ++m) {
                const float v0 = fmaxf(fmaf((t1a[m][0] - mean1) * rstd1, g1v[m].x, be1v[m].x), 0.f);
                const float v1 = fmaxf(fmaf((t1a[m][1] - mean1) * rstd1, g1v[m].y, be1v[m].y), 0.f);
                const float v2 = fmaxf(fmaf((t1a[m][2] - mean1) * rstd1, g1v[m].z, be1v[m].z), 0.f);
                const float v3 = fmaxf(fmaf((t1a[m][3] - mean1) * rstd1, g1v[m].w, be1v[m].w), 0.f);
                pw[2 * m]     = cvtpk(v0, v1);
                pw[2 * m + 1] = cvtpk(v2, v3);
            }
            const u32x4 r0 = {pw[0], pw[1], pw[2], pw[3]};
            const u32x4 r1 = {pw[4], pw[5], pw[6], pw[7]};
            const bf16x8 rb0 = __builtin_bit_cast(bf16x8, r0);
            const bf16x8 rb1 = __builtin_bit_cast(bf16x8, r1);

            f32x4 a2 = __builtin_amdgcn_mfma_f32_16x16x32_bf16(w2f[0], rb0, z, 0, 0, 0);
            a2 = __builtin_amdgcn_mfma_f32_16x16x32_bf16(w2f[1], rb1, a2, 0, 0, 0);
            a2[0] += b2v.x; a2[1] += b2v.y; a2[2] += b2v.z; a2[3] += b2v.w;

            // LN over C=16
            float s2 = (a2[0] + a2[1]) + (a2[2] + a2[3]);
            float q2 = fmaf(a2[0], a2[0], fmaf(a2[1], a2[1],
                       fmaf(a2[2], a2[2], a2[3] * a2[3])));
            s2 += __shfl_xor(s2, 16);  q2 += __shfl_xor(q2, 16);
            s2 += __shfl_xor(s2, 32);  q2 += __shfl_xor(q2, 32);
            const float mean2 = s2 * (1.f / C);
            const float var2  = fmaxf(q2 * (1.f / C) - mean2 * mean2, 0.f);
            const float rstd2 = rsqrtf(var2 + EPSF);
            const float vm = ((it << 4) + q < rem) ? 1.f : 0.f;
            lacc[0] += fmaxf(fmaf((a2[0] - mean2) * rstd2, g2v.x, be2v.x), 0.f) * vm;
            lacc[1] += fmaxf(fmaf((a2[1] - mean2) * rstd2, g2v.y, be2v.y), 0.f) * vm;
            lacc[2] += fmaxf(fmaf((a2[2] - mean2) * rstd2, g2v.z, be2v.z), 0.f) * vm;
            lacc[3] += fmaxf(fmaf((a2[3] - mean2) * rstd2, g2v.w, be2v.w), 0.f) * vm;
        }

        // pool over the 16 point-columns; lane (g, q==0) writes c = 4g..4g+3
        #pragma unroll
        for (int off = 1; off < 16; off <<= 1) {
            #pragma unroll
            for (int r = 0; r < 4; ++r) lacc[r] += __shfl_xor(lacc[r], off);
        }
        if (q == 0)
            *(float4*)(part + (size_t)u * C + 4 * g) =
                make_float4(lacc[0], lacc[1], lacc[2], lacc[3]);
    }
}

// ---------- K3: encoder MLP per batch ----------
__global__ __launch_bounds__(EH) void k_enc(
    const float* __restrict__ part, const int* __restrict__ cnt,
    const float* __restrict__ We1, const float* __restrict__ bb1,
    const float* __restrict__ gg1, const float* __restrict__ bbe1,
    const float* __restrict__ We2, const float* __restrict__ bb2,
    const float* __restrict__ gg2, const float* __restrict__ bbe2,
    float* __restrict__ out)
{
    const int b = blockIdx.x;
    const int t = threadIdx.x;
    __shared__ int sP[64];
    __shared__ float red[8][16];
    __shared__ float cc[C];
    __shared__ float stats[2];
    __shared__ float buf[EH];
    __shared__ float buf2[2 * L];

    if (t < 64) {
        int p = (cnt[t] + 63) >> 6;
        #pragma unroll
        for (int off = 1; off < 64; off <<= 1) {
            const int pv = __shfl_up(p, off);
            if (t >= off) p += pv;
        }
        sP[t] = p;
    }
    __syncthreads();
    const int n = cnt[b];
    const int row0 = (b == 0) ? 0 : sP[b - 1];
    const int rows = sP[b] - row0;

    {
        const int c = t & 15, s = t >> 4;
        float ps = 0.f;
        for (int r = s; r < rows; r += 8)
            ps += part[(size_t)(row0 + r) * C + c];
        red[s][c] = ps;
    }
    __syncthreads();
    if (t < C) {
        float v = 0.f;
        #pragma unroll
        for (int s = 0; s < 8; ++s) v += red[s][t];
        cc[t] = v;
    }
    __syncthreads();
    const float inv = 1.f / fmaxf((float)n, 1.f);

    float v1 = bb1[t];
    #pragma unroll
    for (int c = 0; c < C; ++c)
        v1 = fmaf(cc[c] * inv, We1[c * EH + t], v1);
    buf[t] = v1;
    __syncthreads();
    if (t == 0) {
        float s = 0.f, ss = 0.f;
        for (int j2 = 0; j2 < EH; ++j2) { s += buf[j2]; ss = fmaf(buf[j2], buf[j2], ss); }
        float mn = s * (1.f / EH);
        float vr = fmaxf(ss * (1.f / EH) - mn * mn, 0.f);
        stats[0] = mn; stats[1] = rsqrtf(vr + EPSF);
    }
    __syncthreads();
    float e1 = fmaxf(fmaf((v1 - stats[0]) * stats[1], gg1[t], bbe1[t]), 0.f);
    __syncthreads();
    buf[t] = e1;
    __syncthreads();

    float v2 = 0.f;
    if (t < 2 * L) {
        v2 = bb2[t];
        #pragma unroll
        for (int h = 0; h < EH; ++h)
            v2 = fmaf(buf[h], We2[h * (2 * L) + t], v2);
        buf2[t] = v2;
    }
    __syncthreads();
    if (t == 0) {
        float s = 0.f, ss = 0.f;
        for (int j2 = 0; j2 < 2 * L; ++j2) { s += buf2[j2]; ss = fmaf(buf2[j2], buf2[j2], ss); }
        float mn = s * (1.f / (2 * L));
        float vr = fmaxf(ss * (1.f / (2 * L)) - mn * mn, 0.f);
        stats[0] = mn; stats[1] = rsqrtf(vr + EPSF);
    }
    __syncthreads();
    if (t < 2 * L) {
        float e2 = fmaxf(fmaf((v2 - stats[0]) * stats[1], gg2[t], bbe2[t]), 0.f);
        if (t < L) out[(size_t)b * L + t]                       = e2;  // mu
        else       out[(size_t)B * L + (size_t)b * L + (t - L)] = e2;  // logvar
    }
}

extern "C" void kernel_launch(void* const* d_in, const int* in_sizes, int n_in,
                              void* d_out, int out_size, void* d_ws, size_t ws_size,
                              hipStream_t stream) {
    const float* x    = (const float*)d_in[0];
    const int*   mask = (const int*)d_in[1];
    const float* fe   = (const float*)d_in[2];
    const float* W1   = (const float*)d_in[3];
    const float* b1   = (const float*)d_in[4];
    const float* g1   = (const float*)d_in[5];
    const float* be1  = (const float*)d_in[6];
    const float* W2   = (const float*)d_in[7];
    const float* b2   = (const float*)d_in[8];
    const float* g2   = (const float*)d_in[9];
    const float* be2  = (const float*)d_in[10];
    const float* We1  = (const float*)d_in[11];
    const float* bb1  = (const float*)d_in[12];
    const float* gg1  = (const float*)d_in[13];
    const float* bbe1 = (const float*)d_in[14];
    const float* We2  = (const float*)d_in[15];
    const float* bb2  = (const float*)d_in[16];
    const float* gg2  = (const float*)d_in[17];
    const float* bbe2 = (const float*)d_in[18];
    float* out = (float*)d_out;

    char* wp = (char*)d_ws;
    float* part     = (float*)wp;               wp += (size_t)MAXU * C * 4;     // 1.28 MB
    int*   cnt      = (int*)wp;                 wp += (size_t)B * 4;            // 256 B
    unsigned short* W1T = (unsigned short*)wp;  wp += (size_t)H * 32 * 2;       // 4 KB
    unsigned short* W2T = (unsigned short*)wp;  wp += (size_t)C * H * 2;        // 2 KB
    unsigned int*   hxp = (unsigned int*)wp;    wp += (size_t)B * D * 4;        // 5.12 MB
    unsigned short* hfe = (unsigned short*)wp;  /* B*D*32 B = 41 MB */

    hipLaunchKernelGGL(k_prep, dim3(B + 2), dim3(1024), 0, stream,
                       mask, x, fe, W1, b1, W2, cnt, hfe, hxp, W1T, W2T);
    hipLaunchKernelGGL(k_rows, dim3(NB), dim3(256), 0, stream,
                       cnt, hfe, hxp, W1T, W2T, g1, be1, g2, be2, b2, part);
    hipLaunchKernelGGL(k_enc, dim3(B), dim3(EH), 0, stream,
                       part, cnt, We1, bb1, gg1, bbe1, We2, bb2, gg2, bbe2, out);
}

// Round 9
// 51.576 us; speedup vs baseline: 2.3130x; 2.3130x over previous
//
#include <hip/hip_runtime.h>
#include <hip/hip_bf16.h>

#define EPSF 1e-5f

namespace {
constexpr int B = 64, D = 20000, C = 16, H = 64, EH = 128, L = 32;
constexpr int DPAD = ((D + 63) / 64) * 64;      // 20032, per-batch compacted stride
constexpr int NB = 2560;                        // k_rows blocks -> 10240 waves
constexpr int FB = 14;                          // febf-conversion blocks
constexpr int MAXU = B * (DPAD / 64);           // max 64-pt units
}

typedef __attribute__((ext_vector_type(8))) short bf16x8;
typedef __attribute__((ext_vector_type(4))) float f32x4;
typedef __attribute__((ext_vector_type(4))) unsigned int u32x4;

static __device__ __forceinline__ unsigned short f2bf(float f) {
    __hip_bfloat16 h = __float2bfloat16(f);
    return __builtin_bit_cast(unsigned short, h);
}
static __device__ __forceinline__ unsigned int packbf(float lo, float hi) {
    return ((unsigned int)f2bf(hi) << 16) | (unsigned int)f2bf(lo);
}
// pair conversion -> v_cvt_pk_bf16_f32 (component-wise bit_cast)
static __device__ __forceinline__ unsigned int cvtpk(float lo, float hi) {
    __hip_bfloat162 h2 = __float22bfloat162_rn(make_float2(lo, hi));
    return ((unsigned int)__builtin_bit_cast(unsigned short, h2.y) << 16)
         | (unsigned int)__builtin_bit_cast(unsigned short, h2.x);
}

// ---------- K1: single-pass compaction (no serialized rounds) + prep ----------
// Blocks 0..B-1: batch b. Each thread loads its 20 mask/x values up-front
// (latencies overlap), one block scan, then contiguous writes in thread-major
// deterministic order. Also packs hxp={bf16(x),1.0}. Blocks B,B+1: W1T/W2T.
// Blocks B+2..: fe -> bf16 table (640 KB, L2-resident for k_rows).
__global__ __launch_bounds__(1024) void k_prep(
    const int* __restrict__ mask, const float* __restrict__ x,
    const float* __restrict__ fe,
    const float* __restrict__ W1, const float* __restrict__ b1,
    const float* __restrict__ W2,
    int* __restrict__ cnt,
    unsigned short* __restrict__ cd, unsigned int* __restrict__ hxp,
    unsigned short* __restrict__ febf,
    unsigned short* __restrict__ W1T, unsigned short* __restrict__ W2T)
{
    const int t = threadIdx.x;
    if (blockIdx.x < B) {
        const int b = blockIdx.x;
        const size_t bD = (size_t)b * D;
        const size_t bP = (size_t)b * DPAD;
        constexpr int NIT = (D + 1023) / 1024;   // 20
        int   mv[NIT];
        float xv[NIT];
        #pragma unroll
        for (int it = 0; it < NIT; ++it) {
            const int d = it * 1024 + t;
            const bool in = d < D;
            mv[it] = in ? mask[bD + d] : 0;
            xv[it] = in ? x[bD + d] : 0.f;
        }
        int cl = 0;
        #pragma unroll
        for (int it = 0; it < NIT; ++it) cl += (mv[it] != 0) ? 1 : 0;

        // block exclusive scan of per-thread counts
        const int lane = t & 63, wid = t >> 6;
        int inc = cl;
        #pragma unroll
        for (int off = 1; off < 64; off <<= 1) {
            const int v = __shfl_up(inc, off);
            if (lane >= off) inc += v;
        }
        __shared__ int ls[16];
        if (lane == 63) ls[wid] = inc;
        __syncthreads();
        int wbase = 0, tot = 0;
        #pragma unroll
        for (int k = 0; k < 16; ++k) {
            const int v = ls[k];
            tot += v;
            if (k < wid) wbase += v;
        }
        int pos = wbase + (inc - cl);

        #pragma unroll
        for (int it = 0; it < NIT; ++it) {
            if (mv[it]) {
                cd[bP + pos]  = (unsigned short)(it * 1024 + t);
                hxp[bP + pos] = packbf(xv[it], 1.0f);
                ++pos;
            }
        }
        // zero-pad to unit boundary (finite garbage-free tail)
        const int padend = (tot + 63) & ~63;
        for (int i = tot + t; i < padend; i += 1024) {
            cd[bP + i] = 0;
            hxp[bP + i] = 0u;
        }
        if (t == 0) cnt[b] = tot;
    } else if (blockIdx.x == B) {
        // W1T with permuted row->h so layer1 D-layout == layer2 B-layout:
        // row rIdx=16m+rho -> h = 32*(m>>1) + 8*(rho>>2) + 4*(m&1) + (rho&3)
        // cols kk: kk<16 -> W1[kk+1][h]; 16 -> W1[0][h] (x); 17 -> b1[h]; else 0
        for (int e = t; e < H * 32; e += 1024) {
            const int rIdx = e >> 5, kk = e & 31;
            const int m = rIdx >> 4, rho = rIdx & 15;
            const int h = 32 * (m >> 1) + 8 * (rho >> 2) + 4 * (m & 1) + (rho & 3);
            float v = 0.f;
            if (kk < 16)       v = W1[(kk + 1) * H + h];
            else if (kk == 16) v = W1[h];
            else if (kk == 17) v = b1[h];
            W1T[e] = f2bf(v);
        }
    } else if (blockIdx.x == B + 1) {
        // W2T[c][h] = W2[h][c]
        for (int e = t; e < C * H; e += 1024) {
            const int c0 = e >> 6, hh = e & 63;
            W2T[e] = f2bf(W2[hh * C + c0]);
        }
    } else {
        const int pb = blockIdx.x - (B + 2);
        for (int u = pb * 1024 + t; u < (D * C) / 8; u += FB * 1024) {
            const float4 f0 = *(const float4*)(fe + (size_t)u * 8);
            const float4 f1 = *(const float4*)(fe + (size_t)u * 8 + 4);
            uint4 pk;
            pk.x = packbf(f0.x, f0.y); pk.y = packbf(f0.z, f0.w);
            pk.z = packbf(f1.x, f1.y); pk.w = packbf(f1.z, f1.w);
            *(uint4*)(febf + (size_t)u * 8) = pk;
        }
    }
}

// ---------- K2: LDS-free MFMA pointnet, ~1 unit per wave ----------
__global__ __launch_bounds__(256, 4) void k_rows(
    const int* __restrict__ cnt,
    const unsigned short* __restrict__ cd, const unsigned int* __restrict__ hxp,
    const unsigned short* __restrict__ febf,
    const unsigned short* __restrict__ W1T, const unsigned short* __restrict__ W2T,
    const float* __restrict__ g1, const float* __restrict__ be1,
    const float* __restrict__ g2, const float* __restrict__ be2,
    const float* __restrict__ b2,
    float* __restrict__ part)      // [MAXU][C]
{
    const int tid = threadIdx.x;
    const int w = tid >> 6, lane = tid & 63;
    const int g = lane >> 4, q = lane & 15;

    // per-lane schedule state (lane == batch id; B == 64)
    const int cv  = cnt[lane];
    const int nuv = (cv + 63) >> 6;
    int Pi = nuv;
    #pragma unroll
    for (int off = 1; off < 64; off <<= 1) {
        const int pv = __shfl_up(Pi, off);
        if (lane >= off) Pi += pv;
    }
    const int T = __shfl(Pi, 63);

    // weight fragments (A-operands)
    bf16x8 w1f[4];
    #pragma unroll
    for (int m = 0; m < 4; ++m)
        w1f[m] = *(const bf16x8*)(W1T + (16 * m + q) * 32 + 8 * g);
    bf16x8 w2f[2];
    #pragma unroll
    for (int ks = 0; ks < 2; ++ks)
        w2f[ks] = *(const bf16x8*)(W2T + q * 64 + 32 * ks + 8 * g);

    // LN1 affine at permuted rows: reg r of tile m holds h = 32(m>>1)+8g+4(m&1)+r
    float4 g1v[4], be1v[4];
    #pragma unroll
    for (int m = 0; m < 4; ++m) {
        const int h0 = 32 * (m >> 1) + 8 * g + 4 * (m & 1);
        g1v[m]  = *(const float4*)(g1  + h0);
        be1v[m] = *(const float4*)(be1 + h0);
    }
    const float4 g2v  = *(const float4*)(g2  + 4 * g);
    const float4 be2v = *(const float4*)(be2 + 4 * g);
    const float4 b2v  = *(const float4*)(b2  + 4 * g);

    const f32x4 z = {0.f, 0.f, 0.f, 0.f};

    for (int u = blockIdx.x * 4 + w; u < T; u += NB * 4) {
        // unit -> (batch b, base offset)
        const unsigned long long bl = __ballot(Pi <= u);
        const int b   = __popcll(bl);
        const int Pb  = __shfl(Pi, b);
        const int nub = __shfl(nuv, b);
        const int n   = __shfl(cv, b);
        const int base = (u - (Pb - nub)) * 64;
        const size_t rowb = (size_t)b * DPAD + base;
        const int rem = n - base;                // valid points in this unit

        // coalesced cd read for all 64 points (pad region is zeroed)
        const int dv = (int)cd[rowb + lane];

        // batch-fetch 4 groups of 16 points -> registers
        bf16x8 hb[4];
        #pragma unroll
        for (int it = 0; it < 4; ++it) {
            const int p = (it << 4) + q;
            const int dd = __shfl(dv, p);
            bf16x8 hv = {0, 0, 0, 0, 0, 0, 0, 0};
            if (g < 2) {
                hv = *(const bf16x8*)(febf + (size_t)dd * 16 + 8 * g);
            } else if (g == 2) {
                const unsigned int xv = hxp[rowb + p];
                const u32x4 tmp = {xv, 0u, 0u, 0u};
                hv = __builtin_bit_cast(bf16x8, tmp);
            }
            hb[it] = hv;
        }

        f32x4 lacc = {0.f, 0.f, 0.f, 0.f};
        #pragma unroll
        for (int it = 0; it < 4; ++it) {
            f32x4 t1a[4];
            #pragma unroll
            for (int m = 0; m < 4; ++m)
                t1a[m] = __builtin_amdgcn_mfma_f32_16x16x32_bf16(w1f[m], hb[it], z, 0, 0, 0);

            // LN over H=64 for point q (disjoint 16-subsets per lane-group)
            float s0 = 0.f, s1 = 0.f, q0 = 0.f, q1 = 0.f;
            #pragma unroll
            for (int m = 0; m < 4; ++m) {
                s0 += t1a[m][0] + t1a[m][1];
                s1 += t1a[m][2] + t1a[m][3];
                q0 = fmaf(t1a[m][0], t1a[m][0], fmaf(t1a[m][1], t1a[m][1], q0));
                q1 = fmaf(t1a[m][2], t1a[m][2], fmaf(t1a[m][3], t1a[m][3], q1));
            }
            float s = s0 + s1, sq = q0 + q1;
            s  += __shfl_xor(s, 16);  sq += __shfl_xor(sq, 16);
            s  += __shfl_xor(s, 32);  sq += __shfl_xor(sq, 32);
            const float mean1 = s * (1.f / H);
            const float var1  = fmaxf(sq * (1.f / H) - mean1 * mean1, 0.f);
            const float rstd1 = rsqrtf(var1 + EPSF);

            // normalize+affine+relu, pack DIRECTLY into layer2 B-fragments
            unsigned int pw[8];
            #pragma unroll
            for (int m = 0; m < 4; ++m) {
                const float v0 = fmaxf(fmaf((t1a[m][0] - mean1) * rstd1, g1v[m].x, be1v[m].x), 0.f);
                const float v1 = fmaxf(fmaf((t1a[m][1] - mean1) * rstd1, g1v[m].y, be1v[m].y), 0.f);
                const float v2 = fmaxf(fmaf((t1a[m][2] - mean1) * rstd1, g1v[m].z, be1v[m].z), 0.f);
                const float v3 = fmaxf(fmaf((t1a[m][3] - mean1) * rstd1, g1v[m].w, be1v[m].w), 0.f);
                pw[2 * m]     = cvtpk(v0, v1);
                pw[2 * m + 1] = cvtpk(v2, v3);
            }
            const u32x4 r0 = {pw[0], pw[1], pw[2], pw[3]};
            const u32x4 r1 = {pw[4], pw[5], pw[6], pw[7]};
            const bf16x8 rb0 = __builtin_bit_cast(bf16x8, r0);
            const bf16x8 rb1 = __builtin_bit_cast(bf16x8, r1);

            f32x4 a2 = __builtin_amdgcn_mfma_f32_16x16x32_bf16(w2f[0], rb0, z, 0, 0, 0);
            a2 = __builtin_amdgcn_mfma_f32_16x16x32_bf16(w2f[1], rb1, a2, 0, 0, 0);
            a2[0] += b2v.x; a2[1] += b2v.y; a2[2] += b2v.z; a2[3] += b2v.w;

            // LN over C=16
            float s2 = (a2[0] + a2[1]) + (a2[2] + a2[3]);
            float q2 = fmaf(a2[0], a2[0], fmaf(a2[1], a2[1],
                       fmaf(a2[2], a2[2], a2[3] * a2[3])));
            s2 += __shfl_xor(s2, 16);  q2 += __shfl_xor(q2, 16);
            s2 += __shfl_xor(s2, 32);  q2 += __shfl_xor(q2, 32);
            const float mean2 = s2 * (1.f / C);
            const float var2  = fmaxf(q2 * (1.f / C) - mean2 * mean2, 0.f);
            const float rstd2 = rsqrtf(var2 + EPSF);
            const float vm = ((it << 4) + q < rem) ? 1.f : 0.f;
            lacc[0] += fmaxf(fmaf((a2[0] - mean2) * rstd2, g2v.x, be2v.x), 0.f) * vm;
            lacc[1] += fmaxf(fmaf((a2[1] - mean2) * rstd2, g2v.y, be2v.y), 0.f) * vm;
            lacc[2] += fmaxf(fmaf((a2[2] - mean2) * rstd2, g2v.z, be2v.z), 0.f) * vm;
            lacc[3] += fmaxf(fmaf((a2[3] - mean2) * rstd2, g2v.w, be2v.w), 0.f) * vm;
        }

        // pool over the 16 point-columns; lane (g, q==0) writes c = 4g..4g+3
        #pragma unroll
        for (int off = 1; off < 16; off <<= 1) {
            #pragma unroll
            for (int r = 0; r < 4; ++r) lacc[r] += __shfl_xor(lacc[r], off);
        }
        if (q == 0)
            *(float4*)(part + (size_t)u * C + 4 * g) =
                make_float4(lacc[0], lacc[1], lacc[2], lacc[3]);
    }
}

// ---------- K3: encoder MLP per batch ----------
__global__ __launch_bounds__(EH) void k_enc(
    const float* __restrict__ part, const int* __restrict__ cnt,
    const float* __restrict__ We1, const float* __restrict__ bb1,
    const float* __restrict__ gg1, const float* __restrict__ bbe1,
    const float* __restrict__ We2, const float* __restrict__ bb2,
    const float* __restrict__ gg2, const float* __restrict__ bbe2,
    float* __restrict__ out)
{
    const int b = blockIdx.x;
    const int t = threadIdx.x;
    __shared__ int sP[64];
    __shared__ float red[8][16];
    __shared__ float cc[C];
    __shared__ float stats[2];
    __shared__ float buf[EH];
    __shared__ float buf2[2 * L];

    if (t < 64) {
        int p = (cnt[t] + 63) >> 6;
        #pragma unroll
        for (int off = 1; off < 64; off <<= 1) {
            const int pv = __shfl_up(p, off);
            if (t >= off) p += pv;
        }
        sP[t] = p;
    }
    __syncthreads();
    const int n = cnt[b];
    const int row0 = (b == 0) ? 0 : sP[b - 1];
    const int rows = sP[b] - row0;

    {
        const int c = t & 15, s = t >> 4;
        float ps = 0.f;
        for (int r = s; r < rows; r += 8)
            ps += part[(size_t)(row0 + r) * C + c];
        red[s][c] = ps;
    }
    __syncthreads();
    if (t < C) {
        float v = 0.f;
        #pragma unroll
        for (int s = 0; s < 8; ++s) v += red[s][t];
        cc[t] = v;
    }
    __syncthreads();
    const float inv = 1.f / fmaxf((float)n, 1.f);

    float v1 = bb1[t];
    #pragma unroll
    for (int c = 0; c < C; ++c)
        v1 = fmaf(cc[c] * inv, We1[c * EH + t], v1);
    buf[t] = v1;
    __syncthreads();
    if (t == 0) {
        float s = 0.f, ss = 0.f;
        for (int j2 = 0; j2 < EH; ++j2) { s += buf[j2]; ss = fmaf(buf[j2], buf[j2], ss); }
        float mn = s * (1.f / EH);
        float vr = fmaxf(ss * (1.f / EH) - mn * mn, 0.f);
        stats[0] = mn; stats[1] = rsqrtf(vr + EPSF);
    }
    __syncthreads();
    float e1 = fmaxf(fmaf((v1 - stats[0]) * stats[1], gg1[t], bbe1[t]), 0.f);
    __syncthreads();
    buf[t] = e1;
    __syncthreads();

    float v2 = 0.f;
    if (t < 2 * L) {
        v2 = bb2[t];
        #pragma unroll
        for (int h = 0; h < EH; ++h)
            v2 = fmaf(buf[h], We2[h * (2 * L) + t], v2);
        buf2[t] = v2;
    }
    __syncthreads();
    if (t == 0) {
        float s = 0.f, ss = 0.f;
        for (int j2 = 0; j2 < 2 * L; ++j2) { s += buf2[j2]; ss = fmaf(buf2[j2], buf2[j2], ss); }
        float mn = s * (1.f / (2 * L));
        float vr = fmaxf(ss * (1.f / (2 * L)) - mn * mn, 0.f);
        stats[0] = mn; stats[1] = rsqrtf(vr + EPSF);
    }
    __syncthreads();
    if (t < 2 * L) {
        float e2 = fmaxf(fmaf((v2 - stats[0]) * stats[1], gg2[t], bbe2[t]), 0.f);
        if (t < L) out[(size_t)b * L + t]                       = e2;  // mu
        else       out[(size_t)B * L + (size_t)b * L + (t - L)] = e2;  // logvar
    }
}

extern "C" void kernel_launch(void* const* d_in, const int* in_sizes, int n_in,
                              void* d_out, int out_size, void* d_ws, size_t ws_size,
                              hipStream_t stream) {
    const float* x    = (const float*)d_in[0];
    const int*   mask = (const int*)d_in[1];
    const float* fe   = (const float*)d_in[2];
    const float* W1   = (const float*)d_in[3];
    const float* b1   = (const float*)d_in[4];
    const float* g1   = (const float*)d_in[5];
    const float* be1  = (const float*)d_in[6];
    const float* W2   = (const float*)d_in[7];
    const float* b2   = (const float*)d_in[8];
    const float* g2   = (const float*)d_in[9];
    const float* be2  = (const float*)d_in[10];
    const float* We1  = (const float*)d_in[11];
    const float* bb1  = (const float*)d_in[12];
    const float* gg1  = (const float*)d_in[13];
    const float* bbe1 = (const float*)d_in[14];
    const float* We2  = (const float*)d_in[15];
    const float* bb2  = (const float*)d_in[16];
    const float* gg2  = (const float*)d_in[17];
    const float* bbe2 = (const float*)d_in[18];
    float* out = (float*)d_out;

    char* wp = (char*)d_ws;
    float* part     = (float*)wp;               wp += (size_t)MAXU * C * 4;     // 1.28 MB
    int*   cnt      = (int*)wp;                 wp += (size_t)B * 4;            // 256 B
    unsigned short* W1T = (unsigned short*)wp;  wp += (size_t)H * 32 * 2;       // 4 KB
    unsigned short* W2T = (unsigned short*)wp;  wp += (size_t)C * H * 2;        // 2 KB
    unsigned short* febf = (unsigned short*)wp; wp += (size_t)D * C * 2;        // 640 KB
    unsigned int*   hxp = (unsigned int*)wp;    wp += (size_t)B * DPAD * 4;     // 5.13 MB
    unsigned short* cd  = (unsigned short*)wp;  /* B*DPAD*2 = 2.56 MB */

    hipLaunchKernelGGL(k_prep, dim3(B + 2 + FB), dim3(1024), 0, stream,
                       mask, x, fe, W1, b1, W2, cnt, cd, hxp, febf, W1T, W2T);
    hipLaunchKernelGGL(k_rows, dim3(NB), dim3(256), 0, stream,
                       cnt, cd, hxp, febf, W1T, W2T, g1, be1, g2, be2, b2, part);
    hipLaunchKernelGGL(k_enc, dim3(B), dim3(EH), 0, stream,
                       part, cnt, We1, bb1, gg1, bbe1, We2, bb2, gg2, bbe2, out);
}